// Round 1
// baseline (161.471 us; speedup 1.0000x reference)
//
#include <hip/hip_runtime.h>

// Simple_TensorProduct (e3nn uvw TP, MUL=256, l<=1, v=1) as two fused bf16 GEMMs.
//   out0[z,w]      = sum_k T0[z,k]   * B0[k,w]   (K=512)
//   out1[(z,c),w]  = sum_k T1[(z,c),k]* B1[k,w]  (K=768, M=3N)
// T = x1 with x2 folded in (built per z-tile, bf16, LDS, A-fragment order).
// B = weights, prescaled by path alphas, bf16, B-fragment order in d_ws.

typedef short bf16x8 __attribute__((ext_vector_type(8)));
typedef float f32x4 __attribute__((ext_vector_type(4)));

static __device__ __forceinline__ unsigned short f2bf(float f) {
  unsigned int u = __builtin_bit_cast(unsigned int, f);
  u += 0x7FFFu + ((u >> 16) & 1u);   // RNE
  return (unsigned short)(u >> 16);
}

static __device__ __forceinline__ bf16x8 asbf(int4 v) {
  return __builtin_bit_cast(bf16x8, v);
}

// ---------------------------------------------------------------------------
// Weight prep: fp32 weights -> prescaled bf16 in MFMA B-operand fragment order.
// B1 region: frag id ((c*12+kt)*16+ct)*64+lane   (24576 frags, 393216 B)
// B0 region: frag id 24576 + ((c*8+kt)*16+ct)*64+lane (16384 frags, 262144 B)
// element e of a frag: k_chunk = kt*32 + (lane>>4)*8 + e, w = ct*16 + (lane&15)
// chunk c covers u in [128c, 128c+128).
// ---------------------------------------------------------------------------
__global__ __launch_bounds__(256) void prep_weights(
    const float* __restrict__ wgt, unsigned short* __restrict__ Bw)
{
  int fid = blockIdx.x * 256 + threadIdx.x;
  union { unsigned short h[8]; int4 v; } pk;
  if (fid < 24576) {
    // B1: seg0->W2*(A1/sqrt3), seg1->W3*(A1/sqrt3), seg2->W5*(A1/sqrt6)
    int lane = fid & 63;
    int ct = (fid >> 6) & 15;
    int q = fid >> 10;            // 0..23
    int kt = q % 12, c = q / 12;
    int w = ct * 16 + (lane & 15);
    int kh = (lane >> 4) * 8;
#pragma unroll
    for (int e = 0; e < 8; ++e) {
      int kc = kt * 32 + kh + e;       // 0..383
      int seg = kc >> 7;
      int u = c * 128 + (kc & 127);
      float s  = (seg == 2) ? 0.025515518153991442f : 0.03608439182435161f;
      int off  = (seg == 0) ? 65536 : (seg == 1 ? 131072 : 262144);
      pk.h[e] = f2bf(wgt[off + u * 256 + w] * s);
    }
    ((int4*)Bw)[fid] = pk.v;
  } else if (fid < 40960) {
    // B0: seg0->W1*A0, seg1->W4*(A0/sqrt3)
    int f2 = fid - 24576;
    int lane = f2 & 63;
    int ct = (f2 >> 6) & 15;
    int q = f2 >> 10;             // 0..15
    int kt = q & 7, c = q >> 3;
    int w = ct * 16 + (lane & 15);
    int kh = (lane >> 4) * 8;
#pragma unroll
    for (int e = 0; e < 8; ++e) {
      int kc = kt * 32 + kh + e;       // 0..255
      int seg = kc >> 7;
      int u = c * 128 + (kc & 127);
      float s  = (seg == 0) ? 0.04419417382415922f : 0.025515518153991442f;
      int off  = (seg == 0) ? 0 : 196608;
      pk.h[e] = f2bf(wgt[off + u * 256 + w] * s);
    }
    ((int4*)Bw)[fid] = pk.v;
  }
}

// ---------------------------------------------------------------------------
// Main kernel: 16 z-rows per block, 256 threads (4 waves), full 256 out-cols.
// LDS holds T fragments for one u-chunk (u-chunk=128): T1 2304 + T0 512 int4 = 44 KB.
// Fragment slot permutation: perm(lane) = lane ^ (kt&7) ^ (lane>>4)  (bijective per
// 64-slot block; balances banks on the scattered ds_write side, read side stays a
// full permutation of 64 consecutive 16B slots -> conflict-free).
// ---------------------------------------------------------------------------
#define T0BASE 2304

__global__ __launch_bounds__(256) void tp_main(
    const float* __restrict__ x1, const float* __restrict__ x2,
    const int4* __restrict__ B1v, const int4* __restrict__ B0v,
    float* __restrict__ out)
{
  __shared__ int4 ldsT[2816];           // 45056 bytes
  const int tid  = threadIdx.x;
  const int lane = tid & 63;
  const int wid  = tid >> 6;            // wave = output col-quarter
  const int z0   = blockIdx.x * 16;

  f32x4 acc1[3][4];
  f32x4 acc0[4];
#pragma unroll
  for (int i = 0; i < 3; ++i)
#pragma unroll
    for (int j = 0; j < 4; ++j) acc1[i][j] = (f32x4){0.f, 0.f, 0.f, 0.f};
#pragma unroll
  for (int j = 0; j < 4; ++j) acc0[j] = (f32x4){0.f, 0.f, 0.f, 0.f};

#pragma unroll 1
  for (int c = 0; c < 2; ++c) {
    if (c) __syncthreads();             // chunk 1 overwrites LDS read by chunk 0 GEMM
    const int ub = c * 128;

    // ---- build T1 fragments: 3 segs x (48 rows x 16 runs) ; row = 3*zl + comp
#pragma unroll
    for (int sg = 0; sg < 3; ++sg) {
#pragma unroll
      for (int sub = 0; sub < 3; ++sub) {
        int rem = sub * 256 + tid;       // 0..767
        int row = rem >> 4;              // 0..47
        int rr  = rem & 15;
        int r   = sg * 16 + rr;          // run 0..47
        int kt  = r >> 2;
        int lh  = r & 3;
        int fl  = (((lh << 4) | (row & 15)) ^ (kt & 7)) ^ lh;
        int addr = (row >> 4) * 768 + kt * 64 + fl;
        int zl = row / 3;
        int k  = row - zl * 3;
        const float* x1r = x1 + (size_t)(z0 + zl) * 1024;
        const float* x2r = x2 + (size_t)(z0 + zl) * 4;
        int u = ub + rr * 8;
        float t[8];
        if (sg == 0) {                   // s1[u] * v2[k]   (-> W2)
          float m = x2r[1 + k];
#pragma unroll
          for (int e = 0; e < 8; ++e) t[e] = x1r[u + e] * m;
        } else if (sg == 1) {            // v1[u,k] * s2    (-> W3)
          float m = x2r[0];
#pragma unroll
          for (int e = 0; e < 8; ++e) t[e] = x1r[256 + 3 * (u + e) + k] * m;
        } else {                         // (v1[u] x v2)[k] (-> W5)
          int k1 = k + 1; if (k1 > 2) k1 -= 3;
          int k2 = k + 2; if (k2 > 2) k2 -= 3;
          float m1 = x2r[1 + k1], m2 = x2r[1 + k2];
#pragma unroll
          for (int e = 0; e < 8; ++e) {
            float va = x1r[256 + 3 * (u + e) + k1];
            float vb = x1r[256 + 3 * (u + e) + k2];
            t[e] = va * m2 - vb * m1;
          }
        }
        union { unsigned short h[8]; int4 v; } pk;
#pragma unroll
        for (int e = 0; e < 8; ++e) pk.h[e] = f2bf(t[e]);
        ldsT[addr] = pk.v;
      }
    }
    // ---- build T0 fragments: 2 segs x (16 rows x 16 runs)
#pragma unroll
    for (int sg = 0; sg < 2; ++sg) {
      int row = tid >> 4;                // 0..15 (= zl)
      int rr  = tid & 15;
      int r   = sg * 16 + rr;
      int kt  = r >> 2;
      int lh  = r & 3;
      int fl  = (((lh << 4) | row) ^ (kt & 7)) ^ lh;
      int addr = T0BASE + kt * 64 + fl;
      const float* x1r = x1 + (size_t)(z0 + row) * 1024;
      const float* x2r = x2 + (size_t)(z0 + row) * 4;
      int u = ub + rr * 8;
      float t[8];
      if (sg == 0) {                     // s1[u] * s2      (-> W1)
        float m = x2r[0];
#pragma unroll
        for (int e = 0; e < 8; ++e) t[e] = x1r[u + e] * m;
      } else {                           // v1[u] . v2      (-> W4)
        float m0 = x2r[1], m1 = x2r[2], m2 = x2r[3];
#pragma unroll
        for (int e = 0; e < 8; ++e) {
          const float* p = x1r + 256 + 3 * (u + e);
          t[e] = p[0] * m0 + p[1] * m1 + p[2] * m2;
        }
      }
      union { unsigned short h[8]; int4 v; } pk;
#pragma unroll
      for (int e = 0; e < 8; ++e) pk.h[e] = f2bf(t[e]);
      ldsT[addr] = pk.v;
    }
    __syncthreads();

    // ---- GEMM out1: 12 K-steps, reg double-buffered A (LDS) + B (global/L2)
    {
      int4 a[3], b[4];
      {
        int fl = lane ^ (lane >> 4);
        a[0] = ldsT[0 * 768 + fl];
        a[1] = ldsT[1 * 768 + fl];
        a[2] = ldsT[2 * 768 + fl];
        const int4* bp = B1v + ((size_t)(c * 12) * 16 + wid * 4) * 64 + lane;
        b[0] = bp[0]; b[1] = bp[64]; b[2] = bp[128]; b[3] = bp[192];
      }
#pragma unroll 1
      for (int kt = 0; kt < 12; ++kt) {
        int4 an[3], bn[4];
        if (kt < 11) {
          int fl = (lane ^ ((kt + 1) & 7)) ^ (lane >> 4);
          an[0] = ldsT[0 * 768 + (kt + 1) * 64 + fl];
          an[1] = ldsT[1 * 768 + (kt + 1) * 64 + fl];
          an[2] = ldsT[2 * 768 + (kt + 1) * 64 + fl];
          const int4* np = B1v + ((size_t)(c * 12 + kt + 1) * 16 + wid * 4) * 64 + lane;
          bn[0] = np[0]; bn[1] = np[64]; bn[2] = np[128]; bn[3] = np[192];
        } else {
          an[0] = a[0]; an[1] = a[1]; an[2] = a[2];
          bn[0] = b[0]; bn[1] = b[1]; bn[2] = b[2]; bn[3] = b[3];
        }
#pragma unroll
        for (int i = 0; i < 3; ++i) {
          bf16x8 av = asbf(a[i]);
#pragma unroll
          for (int j = 0; j < 4; ++j)
            acc1[i][j] = __builtin_amdgcn_mfma_f32_16x16x32_bf16(
                av, asbf(b[j]), acc1[i][j], 0, 0, 0);
        }
        a[0] = an[0]; a[1] = an[1]; a[2] = an[2];
        b[0] = bn[0]; b[1] = bn[1]; b[2] = bn[2]; b[3] = bn[3];
      }
    }
    // ---- GEMM out0: 8 K-steps
    {
      int4 a0, b[4];
      {
        int fl = lane ^ (lane >> 4);
        a0 = ldsT[T0BASE + fl];
        const int4* bp = B0v + ((size_t)(c * 8) * 16 + wid * 4) * 64 + lane;
        b[0] = bp[0]; b[1] = bp[64]; b[2] = bp[128]; b[3] = bp[192];
      }
#pragma unroll 1
      for (int kt = 0; kt < 8; ++kt) {
        int4 an, bn[4];
        if (kt < 7) {
          int fl = (lane ^ ((kt + 1) & 7)) ^ (lane >> 4);
          an = ldsT[T0BASE + (kt + 1) * 64 + fl];
          const int4* np = B0v + ((size_t)(c * 8 + kt + 1) * 16 + wid * 4) * 64 + lane;
          bn[0] = np[0]; bn[1] = np[64]; bn[2] = np[128]; bn[3] = np[192];
        } else {
          an = a0; bn[0] = b[0]; bn[1] = b[1]; bn[2] = b[2]; bn[3] = b[3];
        }
        bf16x8 av = asbf(a0);
#pragma unroll
        for (int j = 0; j < 4; ++j)
          acc0[j] = __builtin_amdgcn_mfma_f32_16x16x32_bf16(
              av, asbf(b[j]), acc0[j], 0, 0, 0);
        a0 = an; b[0] = bn[0]; b[1] = bn[1]; b[2] = bn[2]; b[3] = bn[3];
      }
    }
  }

  // ---- epilogue: accumulators are the final outputs
  const int col = lane & 15;
  const int rb  = (lane >> 4) * 4;       // C/D: col=lane&15, row=(lane>>4)*4+reg
#pragma unroll
  for (int j = 0; j < 4; ++j) {
    int w = (wid * 4 + j) * 16 + col;
#pragma unroll
    for (int rg = 0; rg < 4; ++rg) {
      int row = rb + rg;                 // zl
      out[(size_t)(z0 + row) * 1024 + w] = acc0[j][rg];
    }
  }
#pragma unroll
  for (int i = 0; i < 3; ++i) {
#pragma unroll
    for (int j = 0; j < 4; ++j) {
      int w = (wid * 4 + j) * 16 + col;
#pragma unroll
      for (int rg = 0; rg < 4; ++rg) {
        int row = i * 16 + rb + rg;      // 0..47 ; row = 3*zl + k
        int zl = row / 3;
        int k  = row - zl * 3;
        out[(size_t)(z0 + zl) * 1024 + 256 + w * 3 + k] = acc1[i][j][rg];
      }
    }
  }
}

// ---------------------------------------------------------------------------
extern "C" void kernel_launch(void* const* d_in, const int* in_sizes, int n_in,
                              void* d_out, int out_size, void* d_ws, size_t ws_size,
                              hipStream_t stream) {
  const float* x1  = (const float*)d_in[0];   // (n, 1024) f32
  const float* x2  = (const float*)d_in[1];   // (n, 4)    f32
  const float* wgt = (const float*)d_in[2];   // (327680,) f32
  float* out = (float*)d_out;                 // (n, 1024) f32

  // ws: B1 fragments [0, 393216) + B0 fragments [393216, 655360)  (bf16)
  unsigned short* Bw = (unsigned short*)d_ws;
  const int4* B1v = (const int4*)Bw;
  const int4* B0v = B1v + 24576;

  int n = in_sizes[0] / 1024;                 // 20000 (divisible by 16)

  prep_weights<<<160, 256, 0, stream>>>(wgt, Bw);
  tp_main<<<n / 16, 256, 0, stream>>>(x1, x2, B1v, B0v, out);
}

// Round 2
// 79.232 us; speedup vs baseline: 2.0380x; 2.0380x over previous
//
#include <hip/hip_runtime.h>

// Simple_TensorProduct (e3nn uvw TP, MUL=256, l<=1, v=1) as two fused bf16 GEMMs.
//   out0[z,w]      = sum_k T0[z,k]    * B0[k,w]   (K=512)
//   out1[(z,c),w]  = sum_k T1[(z,c),k]* B1[k,w]   (K=768, M=3N)
// T = x1 with x2 folded in (built per z-tile, bf16, LDS, A-fragment order).
// B = weights, prescaled by path alphas, bf16, B-fragment order in d_ws.
//
// R2: T-build restructured for coalesced vectorized x1 loads (thread (zl,rr)
// owns u-run [rr*8, rr*8+8): 2+6 dwordx4 contiguous, computes all 11 fragment
// rows) + both u-chunks' x1 loads issued at kernel start (chunk-1 latency
// hidden under build-0/GEMM-0). Fragment/GEMM/epilogue math identical to R1.

typedef short bf16x8 __attribute__((ext_vector_type(8)));
typedef float f32x4 __attribute__((ext_vector_type(4)));

static __device__ __forceinline__ unsigned short f2bf(float f) {
  unsigned int u = __builtin_bit_cast(unsigned int, f);
  u += 0x7FFFu + ((u >> 16) & 1u);   // RNE
  return (unsigned short)(u >> 16);
}

static __device__ __forceinline__ bf16x8 asbf(int4 v) {
  return __builtin_bit_cast(bf16x8, v);
}

// ---------------------------------------------------------------------------
// Weight prep: fp32 weights -> prescaled bf16 in MFMA B-operand fragment order.
// B1 region: frag id ((c*12+kt)*16+ct)*64+lane   (24576 frags, 393216 B)
// B0 region: frag id 24576 + ((c*8+kt)*16+ct)*64+lane (16384 frags, 262144 B)
// element e of a frag: k_chunk = kt*32 + (lane>>4)*8 + e, w = ct*16 + (lane&15)
// chunk c covers u in [128c, 128c+128).
// ---------------------------------------------------------------------------
__global__ __launch_bounds__(256) void prep_weights(
    const float* __restrict__ wgt, unsigned short* __restrict__ Bw)
{
  int fid = blockIdx.x * 256 + threadIdx.x;
  union { unsigned short h[8]; int4 v; } pk;
  if (fid < 24576) {
    // B1: seg0->W2*(A1/sqrt3), seg1->W3*(A1/sqrt3), seg2->W5*(A1/sqrt6)
    int lane = fid & 63;
    int ct = (fid >> 6) & 15;
    int q = fid >> 10;            // 0..23
    int kt = q % 12, c = q / 12;
    int w = ct * 16 + (lane & 15);
    int kh = (lane >> 4) * 8;
#pragma unroll
    for (int e = 0; e < 8; ++e) {
      int kc = kt * 32 + kh + e;       // 0..383
      int seg = kc >> 7;
      int u = c * 128 + (kc & 127);
      float s  = (seg == 2) ? 0.025515518153991442f : 0.03608439182435161f;
      int off  = (seg == 0) ? 65536 : (seg == 1 ? 131072 : 262144);
      pk.h[e] = f2bf(wgt[off + u * 256 + w] * s);
    }
    ((int4*)Bw)[fid] = pk.v;
  } else if (fid < 40960) {
    // B0: seg0->W1*A0, seg1->W4*(A0/sqrt3)
    int f2 = fid - 24576;
    int lane = f2 & 63;
    int ct = (f2 >> 6) & 15;
    int q = f2 >> 10;             // 0..15
    int kt = q & 7, c = q >> 3;
    int w = ct * 16 + (lane & 15);
    int kh = (lane >> 4) * 8;
#pragma unroll
    for (int e = 0; e < 8; ++e) {
      int kc = kt * 32 + kh + e;       // 0..255
      int seg = kc >> 7;
      int u = c * 128 + (kc & 127);
      float s  = (seg == 0) ? 0.04419417382415922f : 0.025515518153991442f;
      int off  = (seg == 0) ? 0 : 196608;
      pk.h[e] = f2bf(wgt[off + u * 256 + w] * s);
    }
    ((int4*)Bw)[fid] = pk.v;
  }
}

#define T0BASE 2304

struct X1Regs {
  float4 s[2];   // s1[u .. u+8)
  float4 v[6];   // v1[(u..u+8), 0..3) interleaved: f[3e+k]
};

static __device__ __forceinline__ void load_x1(
    X1Regs& r, const float* __restrict__ x1, int zrow, int ub, int rr)
{
  const float* base = x1 + (size_t)zrow * 1024;
  const float4* ps = (const float4*)(base + ub + rr * 8);
  r.s[0] = ps[0]; r.s[1] = ps[1];
  const float4* pv = (const float4*)(base + 256 + 3 * ub + rr * 24);
#pragma unroll
  for (int i = 0; i < 6; ++i) r.v[i] = pv[i];
}

static __device__ __forceinline__ void build_frags(
    const X1Regs& r, int zl, int rr, float s2, const float* v2, int4* ldsT)
{
  union { float4 q[2]; float f[8]; } s1u;
  s1u.q[0] = r.s[0]; s1u.q[1] = r.s[1];
  union { float4 q[6]; float f[24]; } v1u;
#pragma unroll
  for (int i = 0; i < 6; ++i) v1u.q[i] = r.v[i];
  const int lh = rr & 3;
  const int kq = rr >> 2;

  // ---- T1: seg 0..2 x comp k 0..2 ; row = 3*zl + k
#pragma unroll
  for (int sg = 0; sg < 3; ++sg) {
#pragma unroll
    for (int k = 0; k < 3; ++k) {
      int row = 3 * zl + k;
      int kt  = sg * 4 + kq;
      int fl  = (((lh << 4) | (row & 15)) ^ (kt & 7)) ^ lh;
      int addr = (row >> 4) * 768 + kt * 64 + fl;
      float t[8];
      if (sg == 0) {                     // s1 * v2[k]      (-> W2)
#pragma unroll
        for (int e = 0; e < 8; ++e) t[e] = s1u.f[e] * v2[k];
      } else if (sg == 1) {              // v1[.,k] * s2    (-> W3)
#pragma unroll
        for (int e = 0; e < 8; ++e) t[e] = v1u.f[3 * e + k] * s2;
      } else {                           // (v1 x v2)[k]    (-> W5)
        int k1 = k + 1; if (k1 > 2) k1 -= 3;
        int k2 = k + 2; if (k2 > 2) k2 -= 3;
#pragma unroll
        for (int e = 0; e < 8; ++e)
          t[e] = v1u.f[3 * e + k1] * v2[k2] - v1u.f[3 * e + k2] * v2[k1];
      }
      union { unsigned short h[8]; int4 v; } pk;
#pragma unroll
      for (int e = 0; e < 8; ++e) pk.h[e] = f2bf(t[e]);
      ldsT[addr] = pk.v;
    }
  }
  // ---- T0: seg 0..1 ; row = zl
#pragma unroll
  for (int sg = 0; sg < 2; ++sg) {
    int kt = sg * 4 + kq;
    int fl = (((lh << 4) | zl) ^ (kt & 7)) ^ lh;
    int addr = T0BASE + kt * 64 + fl;
    float t[8];
    if (sg == 0) {                       // s1 * s2         (-> W1)
#pragma unroll
      for (int e = 0; e < 8; ++e) t[e] = s1u.f[e] * s2;
    } else {                             // v1 . v2         (-> W4)
#pragma unroll
      for (int e = 0; e < 8; ++e)
        t[e] = v1u.f[3 * e] * v2[0] + v1u.f[3 * e + 1] * v2[1]
             + v1u.f[3 * e + 2] * v2[2];
    }
    union { unsigned short h[8]; int4 v; } pk;
#pragma unroll
    for (int e = 0; e < 8; ++e) pk.h[e] = f2bf(t[e]);
    ldsT[addr] = pk.v;
  }
}

static __device__ __forceinline__ void gemm_chunk(
    int c, int lane, int wid, const int4* ldsT,
    const int4* __restrict__ B1v, const int4* __restrict__ B0v,
    f32x4 acc1[3][4], f32x4 acc0[4])
{
  // ---- GEMM out1: 12 K-steps, reg double-buffered A (LDS) + B (global/L2)
  {
    int4 a[3], b[4];
    {
      int fl = lane ^ (lane >> 4);
      a[0] = ldsT[0 * 768 + fl];
      a[1] = ldsT[1 * 768 + fl];
      a[2] = ldsT[2 * 768 + fl];
      const int4* bp = B1v + ((size_t)(c * 12) * 16 + wid * 4) * 64 + lane;
      b[0] = bp[0]; b[1] = bp[64]; b[2] = bp[128]; b[3] = bp[192];
    }
#pragma unroll 1
    for (int kt = 0; kt < 12; ++kt) {
      int4 an[3], bn[4];
      if (kt < 11) {
        int fl = (lane ^ ((kt + 1) & 7)) ^ (lane >> 4);
        an[0] = ldsT[0 * 768 + (kt + 1) * 64 + fl];
        an[1] = ldsT[1 * 768 + (kt + 1) * 64 + fl];
        an[2] = ldsT[2 * 768 + (kt + 1) * 64 + fl];
        const int4* np = B1v + ((size_t)(c * 12 + kt + 1) * 16 + wid * 4) * 64 + lane;
        bn[0] = np[0]; bn[1] = np[64]; bn[2] = np[128]; bn[3] = np[192];
      } else {
        an[0] = a[0]; an[1] = a[1]; an[2] = a[2];
        bn[0] = b[0]; bn[1] = b[1]; bn[2] = b[2]; bn[3] = b[3];
      }
#pragma unroll
      for (int i = 0; i < 3; ++i) {
        bf16x8 av = asbf(a[i]);
#pragma unroll
        for (int j = 0; j < 4; ++j)
          acc1[i][j] = __builtin_amdgcn_mfma_f32_16x16x32_bf16(
              av, asbf(b[j]), acc1[i][j], 0, 0, 0);
      }
      a[0] = an[0]; a[1] = an[1]; a[2] = an[2];
      b[0] = bn[0]; b[1] = bn[1]; b[2] = bn[2]; b[3] = bn[3];
    }
  }
  // ---- GEMM out0: 8 K-steps
  {
    int4 a0, b[4];
    {
      int fl = lane ^ (lane >> 4);
      a0 = ldsT[T0BASE + fl];
      const int4* bp = B0v + ((size_t)(c * 8) * 16 + wid * 4) * 64 + lane;
      b[0] = bp[0]; b[1] = bp[64]; b[2] = bp[128]; b[3] = bp[192];
    }
#pragma unroll 1
    for (int kt = 0; kt < 8; ++kt) {
      int4 an, bn[4];
      if (kt < 7) {
        int fl = (lane ^ ((kt + 1) & 7)) ^ (lane >> 4);
        an = ldsT[T0BASE + (kt + 1) * 64 + fl];
        const int4* np = B0v + ((size_t)(c * 8 + kt + 1) * 16 + wid * 4) * 64 + lane;
        bn[0] = np[0]; bn[1] = np[64]; bn[2] = np[128]; bn[3] = np[192];
      } else {
        an = a0; bn[0] = b[0]; bn[1] = b[1]; bn[2] = b[2]; bn[3] = b[3];
      }
      bf16x8 av = asbf(a0);
#pragma unroll
      for (int j = 0; j < 4; ++j)
        acc0[j] = __builtin_amdgcn_mfma_f32_16x16x32_bf16(
            av, asbf(b[j]), acc0[j], 0, 0, 0);
      a0 = an; b[0] = bn[0]; b[1] = bn[1]; b[2] = bn[2]; b[3] = bn[3];
    }
  }
}

// ---------------------------------------------------------------------------
// Main kernel: 16 z-rows per block, 256 threads (4 waves), full 256 out-cols.
// LDS holds T fragments for one u-chunk (u=128): T1 2304 + T0 512 int4 = 44 KB.
// ---------------------------------------------------------------------------
__global__ __launch_bounds__(256, 3) void tp_main(
    const float* __restrict__ x1, const float* __restrict__ x2,
    const int4* __restrict__ B1v, const int4* __restrict__ B0v,
    float* __restrict__ out)
{
  __shared__ int4 ldsT[2816];           // 45056 bytes
  const int tid  = threadIdx.x;
  const int lane = tid & 63;
  const int wid  = tid >> 6;            // wave = output col-quarter
  const int z0   = blockIdx.x * 16;
  const int zl   = tid >> 4;            // T-build row ownership
  const int rr   = tid & 15;            // T-build u-run ownership

  f32x4 acc1[3][4];
  f32x4 acc0[4];
#pragma unroll
  for (int i = 0; i < 3; ++i)
#pragma unroll
    for (int j = 0; j < 4; ++j) acc1[i][j] = (f32x4){0.f, 0.f, 0.f, 0.f};
#pragma unroll
  for (int j = 0; j < 4; ++j) acc0[j] = (f32x4){0.f, 0.f, 0.f, 0.f};

  // x2 row values (broadcast per 16 threads)
  float4 x2v = ((const float4*)x2)[z0 + zl];
  const float s2 = x2v.x;
  float v2[3] = {x2v.y, x2v.z, x2v.w};

  // issue ALL x1 loads up front: chunk-1's 8 dwordx4 stay in flight
  // under build-0 + GEMM-0 (compiler tracks vmcnt counts).
  X1Regs r0, r1;
  load_x1(r0, x1, z0 + zl, 0,   rr);
  load_x1(r1, x1, z0 + zl, 128, rr);

  build_frags(r0, zl, rr, s2, v2, ldsT);
  __syncthreads();
  gemm_chunk(0, lane, wid, ldsT, B1v, B0v, acc1, acc0);
  __syncthreads();
  build_frags(r1, zl, rr, s2, v2, ldsT);
  __syncthreads();
  gemm_chunk(1, lane, wid, ldsT, B1v, B0v, acc1, acc0);

  // ---- epilogue: accumulators are the final outputs
  const int col = lane & 15;
  const int rb  = (lane >> 4) * 4;       // C/D: col=lane&15, row=(lane>>4)*4+reg
#pragma unroll
  for (int j = 0; j < 4; ++j) {
    int w = (wid * 4 + j) * 16 + col;
#pragma unroll
    for (int rg = 0; rg < 4; ++rg) {
      int row = rb + rg;                 // zl
      out[(size_t)(z0 + row) * 1024 + w] = acc0[j][rg];
    }
  }
#pragma unroll
  for (int i = 0; i < 3; ++i) {
#pragma unroll
    for (int j = 0; j < 4; ++j) {
      int w = (wid * 4 + j) * 16 + col;
#pragma unroll
      for (int rg = 0; rg < 4; ++rg) {
        int row = i * 16 + rb + rg;      // 0..47 ; row = 3*zl + k
        int zz = row / 3;
        int k  = row - zz * 3;
        out[(size_t)(z0 + zz) * 1024 + 256 + w * 3 + k] = acc1[i][j][rg];
      }
    }
  }
}

// ---------------------------------------------------------------------------
extern "C" void kernel_launch(void* const* d_in, const int* in_sizes, int n_in,
                              void* d_out, int out_size, void* d_ws, size_t ws_size,
                              hipStream_t stream) {
  const float* x1  = (const float*)d_in[0];   // (n, 1024) f32
  const float* x2  = (const float*)d_in[1];   // (n, 4)    f32
  const float* wgt = (const float*)d_in[2];   // (327680,) f32
  float* out = (float*)d_out;                 // (n, 1024) f32

  // ws: B1 fragments [0, 393216) + B0 fragments [393216, 655360)  (bf16)
  unsigned short* Bw = (unsigned short*)d_ws;
  const int4* B1v = (const int4*)Bw;
  const int4* B0v = B1v + 24576;

  int n = in_sizes[0] / 1024;                 // 20000 (divisible by 16)

  prep_weights<<<160, 256, 0, stream>>>(wgt, Bw);
  tp_main<<<n / 16, 256, 0, stream>>>(x1, x2, B1v, B0v, out);
}